// Round 9
// baseline (312.604 us; speedup 1.0000x reference)
//
#include <hip/hip_runtime.h>

typedef _Float16 h8 __attribute__((ext_vector_type(8)));
typedef _Float16 h2 __attribute__((ext_vector_type(2)));
typedef float f4 __attribute__((ext_vector_type(4)));

#define NHEADS 6
#define LOGMAX 4.6051701859880914f   // ln(100)

// kept position j (0..31) -> row index in window (0..63); kept iff (r+c) even
__device__ __forceinline__ int S_of(int j) { return ((j >> 2) << 3) + ((j & 3) << 1) + ((j >> 2) & 1); }
// complement (masked) position
__device__ __forceinline__ int SC_of(int j) { return ((j >> 2) << 3) + ((j & 3) << 1) + (1 - ((j >> 2) & 1)); }

// 16-lane (DPP row) reductions on the VALU pipe.
template <int CTRL>
__device__ __forceinline__ float dpp_mov(float x) {
    return __builtin_bit_cast(float,
        __builtin_amdgcn_update_dpp(0, __builtin_bit_cast(int, x), CTRL, 0xF, 0xF, true));
}
__device__ __forceinline__ float rowsum16(float x) {
    x += dpp_mov<0x121>(x);   // row_ror:1
    x += dpp_mov<0x122>(x);   // row_ror:2
    x += dpp_mov<0x124>(x);   // row_ror:4
    x += dpp_mov<0x128>(x);   // row_ror:8
    return x;
}
__device__ __forceinline__ float rowmax16(float x) {
    x = fmaxf(x, dpp_mov<0x121>(x));
    x = fmaxf(x, dpp_mov<0x122>(x));
    x = fmaxf(x, dpp_mov<0x124>(x));
    x = fmaxf(x, dpp_mov<0x128>(x));
    return x;
}
__device__ __forceinline__ unsigned pack2(float a, float b) {
    h2 v; v[0] = (_Float16)a; v[1] = (_Float16)b;
    return __builtin_bit_cast(unsigned, v);
}

// ---------------------------------------------------------------------------
// Pack kernel (layouts unchanged from rounds 6-8, all numerically validated).
// qkvp: [h][nt 0..5][ks 0..5][lane][8]
// projp: [ksblk=h][nt 0..11][lane][8], k-dim pair-interleaved per head block
// biask: [h][32][32]
// ---------------------------------------------------------------------------
__global__ void pack_kernel(const float* __restrict__ qkv_w,
                            const float* __restrict__ proj_w,
                            const float* __restrict__ rel_bias_table,
                            const int* __restrict__ rel_pos_index,
                            _Float16* __restrict__ qkvp,
                            _Float16* __restrict__ projp,
                            float* __restrict__ biask) {
    int tid = blockIdx.x * 256 + threadIdx.x;
    const int NQ = 6 * 6 * 6 * 64;        // 13824
    const int NP = 6 * 12 * 64;           // 4608
    if (tid < NQ) {
        int l = tid & 63;
        int rest = tid >> 6;
        int ks = rest % 6;
        int nt = (rest / 6) % 6;
        int h = rest / 36;
        int o = (nt >> 1) * 192 + h * 32 + (nt & 1) * 16 + (l & 15);
        int k0 = ks * 32 + (l >> 4) * 8;
        const float* src = qkv_w + o * 192 + k0;
        _Float16* dst = qkvp + tid * 8;
#pragma unroll
        for (int j = 0; j < 8; ++j) dst[j] = (_Float16)src[j];
    } else if (tid < NQ + NP) {
        int t = tid - NQ;
        int l = t & 63;
        int rest = t >> 6;         // 0..71
        int nt = rest % 12;
        int h = rest / 12;         // k-block (head)
        int o = nt * 16 + (l & 15);
        const float* srcrow = proj_w + o * 192 + h * 32;
        _Float16* dst = projp + t * 8;
        int p0 = (l >> 4) * 8;
#pragma unroll
        for (int j = 0; j < 8; ++j) {
            int p = p0 + j;
            dst[j] = (_Float16)srcrow[(p >> 1) + ((p & 1) << 4)];
        }
    } else if (tid < NQ + NP + 6 * 32 * 32) {
        int t = tid - (NQ + NP);
        int h = t >> 10;
        int jr = (t >> 5) & 31;
        int ic = t & 31;
        int rp = rel_pos_index[S_of(jr) * 64 + S_of(ic)];
        biask[t] = rel_bias_table[rp * NHEADS + h];
    }
}

// ---------------------------------------------------------------------------
// Main fused kernel: 1 block = ONE window, 3 waves (192 thr).
// Wave wv owns heads {wv, wv+3} END-TO-END: qkv GEMM (M=32, xf[2][6] regs),
// norms, QK^T, softmax, PV — all against its own tmpu/knu/vT slices. The head
// loop therefore has ZERO barriers (per-wave LDS ordering is automatic).
// Heads meet only at outSu (disjoint column slices) -> ONE barrier per block,
// then phase C (proj GEMM) splits the 192 output cols across the 3 waves.
// Rounds 6-8 showed no pipe >42% busy with ~18 sync points/block: the
// barrier+phase serialization was the cost, not bandwidth or weight latency.
// LDS 32256 B -> 5 blocks/CU (15 waves); waves_per_eu(4,8) pins <=128 regs.
// ---------------------------------------------------------------------------
__global__ __launch_bounds__(192) __attribute__((amdgpu_waves_per_eu(4, 8)))
void cwa_kernel(
    const float* __restrict__ x,
    const _Float16* __restrict__ qkvp,
    const _Float16* __restrict__ projp,
    const float* __restrict__ biask,
    const float* __restrict__ qkv_b,
    const float* __restrict__ proj_b,
    const float* __restrict__ logit_scale,
    float* __restrict__ out) {
    __shared__ __align__(16) unsigned tmpu[3][32][16];  // per-wave q then p, 6144 B
    __shared__ __align__(16) unsigned knu[3][32][16];   // per-wave k-norm,   6144 B
    __shared__ __align__(16) _Float16 vT[3][32][40];    // per-wave v^T,      7680 B
    __shared__ __align__(16) unsigned outSu[32][96];    // shared O, pair-packed 12288 B
    // total 32256 B -> 5 blocks/CU

    const int tid = threadIdx.x;
    const int lane = tid & 63;
    const int wv = tid >> 6;      // wave 0..2: owns heads wv and wv+3
    const int cl = lane & 15;
    const int g = lane >> 4;
    const long win = blockIdx.x;  // one window per block

    // ---- masked rows: output = proj_b (32 rows x 48 f4 = 1536 jobs) ----
#pragma unroll
    for (int e = tid, it = 0; it < 8; e += 192, ++it) {
        int row = e / 48, c4 = e % 48;
        *(f4*)(out + (win * 64 + SC_of(row)) * 192 + c4 * 4) = *(const f4*)(proj_b + c4 * 4);
    }

    // ---- all 32 kept rows of x -> A-fragment registers (2 m-tiles) ----
    h8 xf[2][6];
#pragma unroll
    for (int mt = 0; mt < 2; ++mt) {
        long xbase = (win * 64 + S_of(mt * 16 + cl)) * 192;
#pragma unroll
        for (int ks = 0; ks < 6; ++ks) {
            f4 u0 = *(const f4*)(x + xbase + ks * 32 + g * 8);
            f4 u1 = *(const f4*)(x + xbase + ks * 32 + g * 8 + 4);
            h8 hv;
            hv[0] = (_Float16)u0[0]; hv[1] = (_Float16)u0[1];
            hv[2] = (_Float16)u0[2]; hv[3] = (_Float16)u0[3];
            hv[4] = (_Float16)u1[0]; hv[5] = (_Float16)u1[1];
            hv[6] = (_Float16)u1[2]; hv[7] = (_Float16)u1[3];
            xf[mt][ks] = hv;
        }
    }

#pragma unroll 1
    for (int hi = 0; hi < 2; ++hi) {
        const int h = wv + hi * 3;
        const _Float16* qb_h = qkvp + (long)h * 18432;   // 6*6*64*8

        float bq0 = qkv_b[h * 32 + cl], bq1 = qkv_b[h * 32 + 16 + cl];
        float bk0 = qkv_b[192 + h * 32 + cl], bk1 = qkv_b[192 + h * 32 + 16 + cl];
        float bv0 = qkv_b[384 + h * 32 + cl], bv1 = qkv_b[384 + h * 32 + 16 + cl];

        // ===== q group: GEMM (24 MFMA) + norm -> tmpu ======================
        {
            f4 acc[2][2];
            acc[0][0] = 0.0f; acc[0][1] = 0.0f; acc[1][0] = 0.0f; acc[1][1] = 0.0f;
#pragma unroll
            for (int ks = 0; ks < 6; ++ks)
#pragma unroll
                for (int nt = 0; nt < 2; ++nt) {
                    h8 b = *(const h8*)(qb_h + (((nt * 6 + ks) * 64 + lane) << 3));
                    acc[0][nt] = __builtin_amdgcn_mfma_f32_16x16x32_f16(xf[0][ks], b, acc[0][nt], 0, 0, 0);
                    acc[1][nt] = __builtin_amdgcn_mfma_f32_16x16x32_f16(xf[1][ks], b, acc[1][nt], 0, 0, 0);
                }
#pragma unroll
            for (int mt = 0; mt < 2; ++mt)
#pragma unroll
                for (int r = 0; r < 4; ++r) {
                    float t0 = acc[mt][0][r] + bq0, t1 = acc[mt][1][r] + bq1;
                    float ss = rowsum16(t0 * t0 + t1 * t1);
                    float rs = 1.0f / fmaxf(sqrtf(ss), 1e-12f);
                    tmpu[wv][mt * 16 + g * 4 + r][cl] = pack2(t0 * rs, t1 * rs);
                }
        }
        // ===== k group: GEMM + norm -> knu =================================
        {
            f4 acc[2][2];
            acc[0][0] = 0.0f; acc[0][1] = 0.0f; acc[1][0] = 0.0f; acc[1][1] = 0.0f;
#pragma unroll
            for (int ks = 0; ks < 6; ++ks)
#pragma unroll
                for (int nt = 0; nt < 2; ++nt) {
                    h8 b = *(const h8*)(qb_h + ((((nt + 2) * 6 + ks) * 64 + lane) << 3));
                    acc[0][nt] = __builtin_amdgcn_mfma_f32_16x16x32_f16(xf[0][ks], b, acc[0][nt], 0, 0, 0);
                    acc[1][nt] = __builtin_amdgcn_mfma_f32_16x16x32_f16(xf[1][ks], b, acc[1][nt], 0, 0, 0);
                }
#pragma unroll
            for (int mt = 0; mt < 2; ++mt)
#pragma unroll
                for (int r = 0; r < 4; ++r) {
                    float t0 = acc[mt][0][r] + bk0, t1 = acc[mt][1][r] + bk1;
                    float ss = rowsum16(t0 * t0 + t1 * t1);
                    float rs = 1.0f / fmaxf(sqrtf(ss), 1e-12f);
                    knu[wv][mt * 16 + g * 4 + r][cl] = pack2(t0 * rs, t1 * rs);
                }
        }
        // ===== v group: GEMM + bias -> vT (pair-interleaved kv) ============
        {
            f4 acc[2][2];
            acc[0][0] = 0.0f; acc[0][1] = 0.0f; acc[1][0] = 0.0f; acc[1][1] = 0.0f;
#pragma unroll
            for (int ks = 0; ks < 6; ++ks)
#pragma unroll
                for (int nt = 0; nt < 2; ++nt) {
                    h8 b = *(const h8*)(qb_h + ((((nt + 4) * 6 + ks) * 64 + lane) << 3));
                    acc[0][nt] = __builtin_amdgcn_mfma_f32_16x16x32_f16(xf[0][ks], b, acc[0][nt], 0, 0, 0);
                    acc[1][nt] = __builtin_amdgcn_mfma_f32_16x16x32_f16(xf[1][ks], b, acc[1][nt], 0, 0, 0);
                }
            // kv = mt*16 + g*4 + r  ->  pos = 2*(g*4+r) + mt
#pragma unroll
            for (int mt = 0; mt < 2; ++mt)
#pragma unroll
                for (int r = 0; r < 4; ++r) {
                    int pos = 2 * (g * 4 + r) + mt;
                    vT[wv][cl][pos] = (_Float16)(acc[mt][0][r] + bv0);
                    vT[wv][16 + cl][pos] = (_Float16)(acc[mt][1][r] + bv1);
                }
        }

        // ===== attention (wave-private, no barriers) =======================
        {
            h8 aq0 = *(const h8*)(&tmpu[wv][cl][g * 4]);
            h8 aq1 = *(const h8*)(&tmpu[wv][16 + cl][g * 4]);
            h8 bk0_ = *(const h8*)(&knu[wv][cl][g * 4]);
            h8 bk1_ = *(const h8*)(&knu[wv][16 + cl][g * 4]);
            f4 s[2][2];
            s[0][0] = 0.0f; s[0][1] = 0.0f; s[1][0] = 0.0f; s[1][1] = 0.0f;
            s[0][0] = __builtin_amdgcn_mfma_f32_16x16x32_f16(aq0, bk0_, s[0][0], 0, 0, 0);
            s[0][1] = __builtin_amdgcn_mfma_f32_16x16x32_f16(aq0, bk1_, s[0][1], 0, 0, 0);
            s[1][0] = __builtin_amdgcn_mfma_f32_16x16x32_f16(aq1, bk0_, s[1][0], 0, 0, 0);
            s[1][1] = __builtin_amdgcn_mfma_f32_16x16x32_f16(aq1, bk1_, s[1][1], 0, 0, 0);

            float scale = __expf(fminf(logit_scale[h], LOGMAX));
#pragma unroll
            for (int mt = 0; mt < 2; ++mt)
#pragma unroll
                for (int r = 0; r < 4; ++r) {
                    int row = mt * 16 + g * 4 + r;
                    float lg0 = s[mt][0][r] * scale + biask[h * 1024 + row * 32 + cl];
                    float lg1 = s[mt][1][r] * scale + biask[h * 1024 + row * 32 + 16 + cl];
                    float mx = rowmax16(fmaxf(lg0, lg1));
                    float e0 = __expf(lg0 - mx);
                    float e1 = __expf(lg1 - mx);
                    float inv = 1.0f / rowsum16(e0 + e1);
                    tmpu[wv][row][cl] = pack2(e0 * inv, e1 * inv);   // overwrites q (consumed)
                }

            h8 ap0 = *(const h8*)(&tmpu[wv][cl][g * 4]);
            h8 ap1 = *(const h8*)(&tmpu[wv][16 + cl][g * 4]);
            h8 bv0_ = *(const h8*)(&vT[wv][cl][g * 8]);
            h8 bv1_ = *(const h8*)(&vT[wv][16 + cl][g * 8]);
            f4 ov[2][2];
            ov[0][0] = 0.0f; ov[0][1] = 0.0f; ov[1][0] = 0.0f; ov[1][1] = 0.0f;
            ov[0][0] = __builtin_amdgcn_mfma_f32_16x16x32_f16(ap0, bv0_, ov[0][0], 0, 0, 0);
            ov[0][1] = __builtin_amdgcn_mfma_f32_16x16x32_f16(ap0, bv1_, ov[0][1], 0, 0, 0);
            ov[1][0] = __builtin_amdgcn_mfma_f32_16x16x32_f16(ap1, bv0_, ov[1][0], 0, 0, 0);
            ov[1][1] = __builtin_amdgcn_mfma_f32_16x16x32_f16(ap1, bv1_, ov[1][1], 0, 0, 0);

            // O -> shared outSu: this wave's disjoint u32 column slice h*16+cl
#pragma unroll
            for (int mt = 0; mt < 2; ++mt)
#pragma unroll
                for (int r = 0; r < 4; ++r)
                    outSu[mt * 16 + g * 4 + r][h * 16 + cl] = pack2(ov[mt][0][r], ov[mt][1][r]);
        }
    }
    __syncthreads();   // the block's ONLY barrier: outSu complete

    // ======== Phase C: proj GEMM; wave wv -> output cols [wv*64, wv*64+64) ==
    {
        f4 pacc[2][4];
#pragma unroll
        for (int mt = 0; mt < 2; ++mt)
#pragma unroll
            for (int nt = 0; nt < 4; ++nt) pacc[mt][nt] = 0.0f;
#pragma unroll
        for (int ks = 0; ks < 6; ++ks) {
            h8 a0 = *(const h8*)(&outSu[cl][ks * 16 + g * 4]);
            h8 a1 = *(const h8*)(&outSu[16 + cl][ks * 16 + g * 4]);
#pragma unroll
            for (int nt = 0; nt < 4; ++nt) {
                h8 b = *(const h8*)(projp + (((ks * 12 + wv * 4 + nt) * 64 + lane) << 3));
                pacc[0][nt] = __builtin_amdgcn_mfma_f32_16x16x32_f16(a0, b, pacc[0][nt], 0, 0, 0);
                pacc[1][nt] = __builtin_amdgcn_mfma_f32_16x16x32_f16(a1, b, pacc[1][nt], 0, 0, 0);
            }
        }
        float pb[4];
#pragma unroll
        for (int nt = 0; nt < 4; ++nt) pb[nt] = proj_b[wv * 64 + nt * 16 + cl];
#pragma unroll
        for (int mt = 0; mt < 2; ++mt)
#pragma unroll
            for (int r = 0; r < 4; ++r) {
                long grow = win * 64 + S_of(mt * 16 + g * 4 + r);
                float* po_ = out + grow * 192 + wv * 64 + cl;
#pragma unroll
                for (int nt = 0; nt < 4; ++nt)
                    po_[nt * 16] = pacc[mt][nt][r] + pb[nt];
            }
    }
}

extern "C" void kernel_launch(void* const* d_in, const int* in_sizes, int n_in,
                              void* d_out, int out_size, void* d_ws, size_t ws_size,
                              hipStream_t stream) {
    const float* x = (const float*)d_in[0];
    const float* qkv_w = (const float*)d_in[1];
    const float* qkv_b = (const float*)d_in[2];
    const float* proj_w = (const float*)d_in[3];
    const float* proj_b = (const float*)d_in[4];
    const float* logit_scale = (const float*)d_in[5];
    const float* rel_bias_table = (const float*)d_in[6];
    const int* rel_pos_index = (const int*)d_in[7];
    float* out = (float*)d_out;

    const int B = in_sizes[0] / (64 * 192);   // number of windows (8192)

    _Float16* qkvp = (_Float16*)d_ws;                 // 13824*8 f16
    _Float16* projp = qkvp + 6 * 6 * 6 * 64 * 8;      // 4608*8 f16
    float* biask = (float*)(projp + 6 * 12 * 64 * 8); // 6*32*32 f32

    pack_kernel<<<96, 256, 0, stream>>>(qkv_w, proj_w, rel_bias_table, rel_pos_index,
                                        qkvp, projp, biask);
    cwa_kernel<<<B, 192, 0, stream>>>(x, qkvp, projp, biask, qkv_b, proj_b,
                                      logit_scale, out);
}

// Round 10
// 218.840 us; speedup vs baseline: 1.4285x; 1.4285x over previous
//
#include <hip/hip_runtime.h>

typedef _Float16 h8 __attribute__((ext_vector_type(8)));
typedef _Float16 h2 __attribute__((ext_vector_type(2)));
typedef float f4 __attribute__((ext_vector_type(4)));

#define NHEADS 6
#define LOGMAX 4.6051701859880914f   // ln(100)
#define LOG2E  1.4426950408889634f

// kept position j (0..31) -> row index in window (0..63); kept iff (r+c) even
__device__ __forceinline__ int S_of(int j) { return ((j >> 2) << 3) + ((j & 3) << 1) + ((j >> 2) & 1); }
// complement (masked) position
__device__ __forceinline__ int SC_of(int j) { return ((j >> 2) << 3) + ((j & 3) << 1) + (1 - ((j >> 2) & 1)); }

// 16-lane (DPP row) reductions on the VALU pipe.
template <int CTRL>
__device__ __forceinline__ float dpp_mov(float x) {
    return __builtin_bit_cast(float,
        __builtin_amdgcn_update_dpp(0, __builtin_bit_cast(int, x), CTRL, 0xF, 0xF, true));
}
__device__ __forceinline__ float rowsum16(float x) {
    x += dpp_mov<0x121>(x);   // row_ror:1
    x += dpp_mov<0x122>(x);   // row_ror:2
    x += dpp_mov<0x124>(x);   // row_ror:4
    x += dpp_mov<0x128>(x);   // row_ror:8
    return x;
}
__device__ __forceinline__ unsigned pack2(float a, float b) {
    h2 v; v[0] = (_Float16)a; v[1] = (_Float16)b;
    return __builtin_bit_cast(unsigned, v);
}
// single-instruction transcendentals (avoid libm div/sqrt expansions)
__device__ __forceinline__ float fast_exp2(float x) {
    float r; asm("v_exp_f32 %0, %1" : "=v"(r) : "v"(x)); return r;
}
__device__ __forceinline__ float fast_rcp(float x) {
    float r; asm("v_rcp_f32 %0, %1" : "=v"(r) : "v"(x)); return r;
}
__device__ __forceinline__ float fast_rsq(float x) {
    float r; asm("v_rsq_f32 %0, %1" : "=v"(r) : "v"(x)); return r;
}

// ---------------------------------------------------------------------------
// Pack kernel.
// qkvp: [h][nt 0..5][ks 0..5][lane][8]
// projp: [ksblk=h][nt 0..11][lane][8], k-dim pair-interleaved per head block
// b2t:  [h][32][32] = (bias - scale_h - 1) * LOG2E   (softmax pre-fold; the
//       constant shift replaces the row-max: logits = cos*scale+bias with
//       |cos|<=1 keeps exp2 args in [-2*scale*log2e-.., -1.3] — in range)
// sl2t: [h] = scale_h * LOG2E,  scale_h = exp(min(logit_scale,LOGMAX))
// ---------------------------------------------------------------------------
__global__ void pack_kernel(const float* __restrict__ qkv_w,
                            const float* __restrict__ proj_w,
                            const float* __restrict__ rel_bias_table,
                            const int* __restrict__ rel_pos_index,
                            const float* __restrict__ logit_scale,
                            _Float16* __restrict__ qkvp,
                            _Float16* __restrict__ projp,
                            float* __restrict__ b2t,
                            float* __restrict__ sl2t) {
    int tid = blockIdx.x * 256 + threadIdx.x;
    const int NQ = 6 * 6 * 6 * 64;        // 13824
    const int NP = 6 * 12 * 64;           // 4608
    if (tid < NQ) {
        int l = tid & 63;
        int rest = tid >> 6;
        int ks = rest % 6;
        int nt = (rest / 6) % 6;
        int h = rest / 36;
        int o = (nt >> 1) * 192 + h * 32 + (nt & 1) * 16 + (l & 15);
        int k0 = ks * 32 + (l >> 4) * 8;
        const float* src = qkv_w + o * 192 + k0;
        _Float16* dst = qkvp + tid * 8;
#pragma unroll
        for (int j = 0; j < 8; ++j) dst[j] = (_Float16)src[j];
    } else if (tid < NQ + NP) {
        int t = tid - NQ;
        int l = t & 63;
        int rest = t >> 6;         // 0..71
        int nt = rest % 12;
        int h = rest / 12;         // k-block (head)
        int o = nt * 16 + (l & 15);
        const float* srcrow = proj_w + o * 192 + h * 32;
        _Float16* dst = projp + t * 8;
        int p0 = (l >> 4) * 8;
#pragma unroll
        for (int j = 0; j < 8; ++j) {
            int p = p0 + j;
            dst[j] = (_Float16)srcrow[(p >> 1) + ((p & 1) << 4)];
        }
    } else if (tid < NQ + NP + 6 * 32 * 32) {
        int t = tid - (NQ + NP);
        int h = t >> 10;
        int jr = (t >> 5) & 31;
        int ic = t & 31;
        int rp = rel_pos_index[S_of(jr) * 64 + S_of(ic)];
        float scale = __expf(fminf(logit_scale[h], LOGMAX));
        b2t[t] = (rel_bias_table[rp * NHEADS + h] - scale - 1.0f) * LOG2E;
        if (jr == 0 && ic == 0) sl2t[h] = scale * LOG2E;
    }
}

// ---------------------------------------------------------------------------
// Main fused kernel: 256 thr = 4 waves = 2 windows; wave (w,mh) owns 16 rows.
// r8 skeleton (global_load_lds weight staging, 3 barriers/head, incremental
// proj pacc) + round-10 VALU cuts: v_rsq/v_rcp for all divisions, constant-
// shift softmax (no row-max; fma+exp per element), 1/sum deferred past PV.
// waves_per_eu(3,8): the ONLY safe pin for this family (4/EU tiers -> 64
// arch VGPRs -> scratch; proven r2/r3/r9).
// ---------------------------------------------------------------------------
__global__ __launch_bounds__(256) __attribute__((amdgpu_waves_per_eu(3, 8)))
void cwa_kernel(
    const float* __restrict__ x,
    const _Float16* __restrict__ qkvp,
    const _Float16* __restrict__ projp,
    const float* __restrict__ b2t,
    const float* __restrict__ sl2t,
    const float* __restrict__ qkv_b,
    const float* __restrict__ proj_b,
    float* __restrict__ out) {
    __shared__ __align__(16) _Float16 wbuf[6 * 6 * 64 * 8];   // 36864 B head tile
    __shared__ __align__(16) unsigned knu[2][32][20];         // 5120 B
    __shared__ __align__(16) _Float16 vT[2][32][40];          // 5120 B
    __shared__ __align__(16) unsigned tmpu[4][16][20];        // 5120 B (q/p/O)
    // total 52224 B -> 3 blocks/CU (12 waves)

    const int tid = threadIdx.x;
    const int lane = tid & 63;
    const int wave = tid >> 6;
    const int cl = lane & 15;
    const int g = lane >> 4;
    const int w0 = blockIdx.x * 2;
    const int w = wave >> 1;    // window within block
    const int mh = wave & 1;    // 16-row m-half within window

    // ---- async-stage head h's weight tile: 9 chunks of 1 KB per wave ----
    auto stage = [&](int h) {
        const _Float16* srcb = qkvp + (long)h * (6 * 6 * 64 * 8) + (wave * 9) * 512 + lane * 8;
        _Float16* dstb = &wbuf[(wave * 9) * 512];
#pragma unroll
        for (int c = 0; c < 9; ++c)
            __builtin_amdgcn_global_load_lds(
                (const __attribute__((address_space(1))) unsigned*)(srcb + c * 512),
                (__attribute__((address_space(3))) unsigned*)(dstb + c * 512),
                16, 0, 0);
    };

    stage(0);   // DMA flies under the prologue below

    // ---- masked rows: output = proj_b ----
    {
        int rowi = tid >> 2;   // 0..63  (2 windows x 32 masked rows)
        int sub = tid & 3;
        long base = ((long)(w0 + (rowi >> 5)) * 64 + SC_of(rowi & 31)) * 192;
#pragma unroll
        for (int i = 0; i < 12; ++i) {
            int c4 = i * 4 + sub;
            *(f4*)(out + base + c4 * 4) = *(const f4*)(proj_b + c4 * 4);
        }
    }

    // ---- load this wave's 16 x-rows into A-fragment registers (fp16) ----
    h8 xf[6];
    {
        long xbase = ((long)(w0 + w) * 64 + S_of(mh * 16 + cl)) * 192;
#pragma unroll
        for (int ks = 0; ks < 6; ++ks) {
            f4 u0 = *(const f4*)(x + xbase + ks * 32 + g * 8);
            f4 u1 = *(const f4*)(x + xbase + ks * 32 + g * 8 + 4);
            h8 hv;
            hv[0] = (_Float16)u0[0]; hv[1] = (_Float16)u0[1];
            hv[2] = (_Float16)u0[2]; hv[3] = (_Float16)u0[3];
            hv[4] = (_Float16)u1[0]; hv[5] = (_Float16)u1[1];
            hv[6] = (_Float16)u1[2]; hv[7] = (_Float16)u1[3];
            xf[ks] = hv;
        }
    }

    f4 pacc[12];
#pragma unroll
    for (int nt = 0; nt < 12; ++nt) pacc[nt] = 0.0f;

#pragma unroll 1
    for (int h = 0; h < NHEADS; ++h) {
        // ---- barrier alpha: everyone's stage DMA for head h has landed ----
        asm volatile("s_waitcnt vmcnt(0)" ::: "memory");
        __builtin_amdgcn_s_barrier();

        // ================= Phase A: qkv GEMM from LDS wbuf ==================
        f4 acc[6];
#pragma unroll
        for (int nt = 0; nt < 6; ++nt) acc[nt] = 0.0f;
#pragma unroll
        for (int ks = 0; ks < 6; ++ks) {
#pragma unroll
            for (int nt = 0; nt < 6; ++nt) {
                h8 b = *(const h8*)(&wbuf[((nt * 6 + ks) * 64 + lane) * 8]);
                acc[nt] = __builtin_amdgcn_mfma_f32_16x16x32_f16(xf[ks], b, acc[nt], 0, 0, 0);
            }
        }
        // ---- barrier beta: all waves done reading wbuf -> safe to overwrite
        asm volatile("s_waitcnt lgkmcnt(0)" ::: "memory");
        __builtin_amdgcn_s_barrier();
        if (h + 1 < NHEADS) stage(h + 1);   // DMA overlaps epilogue + phase B

        // ---- epilogue (registers only; rsq instead of sqrt+div) ----
        float bq0 = qkv_b[h * 32 + cl], bq1 = qkv_b[h * 32 + 16 + cl];
        float bk0 = qkv_b[192 + h * 32 + cl], bk1 = qkv_b[192 + h * 32 + 16 + cl];
        float bv0 = qkv_b[384 + h * 32 + cl], bv1 = qkv_b[384 + h * 32 + 16 + cl];
        unsigned qw[4], kw[4];
        float vv0[4], vv1[4];
#pragma unroll
        for (int r = 0; r < 4; ++r) {
            float t0 = acc[0][r] + bq0, t1 = acc[1][r] + bq1;
            float ss = rowsum16(fmaf(t0, t0, t1 * t1));
            float rs = fast_rsq(fmaxf(ss, 1e-24f));   // == 1/max(sqrt(ss),1e-12)
            qw[r] = pack2(t0 * rs, t1 * rs);
            t0 = acc[2][r] + bk0; t1 = acc[3][r] + bk1;
            ss = rowsum16(fmaf(t0, t0, t1 * t1));
            rs = fast_rsq(fmaxf(ss, 1e-24f));
            kw[r] = pack2(t0 * rs, t1 * rs);
            vv0[r] = acc[4][r] + bv0;
            vv1[r] = acc[5][r] + bv1;
        }
#pragma unroll
        for (int r = 0; r < 4; ++r) {
            int q = g * 4 + r;
            tmpu[wave][q][cl] = qw[r];
            knu[w][mh * 16 + q][cl] = kw[r];
            int kvpos = 2 * q + mh;
            vT[w][cl][kvpos] = (_Float16)vv0[r];
            vT[w][16 + cl][kvpos] = (_Float16)vv1[r];
        }
        // ---- barrier gamma: kn/vT visible; vmcnt NOT drained (DMA in flight)
        asm volatile("s_waitcnt lgkmcnt(0)" ::: "memory");
        __builtin_amdgcn_s_barrier();

        // ================= Phase B: attention + incremental proj ============
        {
            h8 aq = *(const h8*)(&tmpu[wave][cl][g * 4]);
            f4 sN[2];
            sN[0] = 0.0f; sN[1] = 0.0f;
#pragma unroll
            for (int nt = 0; nt < 2; ++nt) {
                h8 bk_ = *(const h8*)(&knu[w][nt * 16 + cl][g * 4]);
                sN[nt] = __builtin_amdgcn_mfma_f32_16x16x32_f16(aq, bk_, sN[nt], 0, 0, 0);
            }
            float sl2 = sl2t[h];
            const float* b2row = b2t + h * 1024 + (mh * 16 + g * 4) * 32;
            unsigned pw[4];
            float invr[4];
#pragma unroll
            for (int r = 0; r < 4; ++r) {
                // e = 2^(s*sl2 + b2) — constant-shift softmax, no row max
                float e0 = fast_exp2(fmaf(sN[0][r], sl2, b2row[r * 32 + cl]));
                float e1 = fast_exp2(fmaf(sN[1][r], sl2, b2row[r * 32 + 16 + cl]));
                invr[r] = rowsum16(e0 + e1);          // raw sum; rcp below
                pw[r] = pack2(e0, e1);                // unnormalized P
            }
#pragma unroll
            for (int r = 0; r < 4; ++r) {
                invr[r] = fast_rcp(invr[r]);
                tmpu[wave][g * 4 + r][cl] = pw[r];
            }
            h8 ap = *(const h8*)(&tmpu[wave][cl][g * 4]);
            f4 ov[2];
            ov[0] = 0.0f; ov[1] = 0.0f;
#pragma unroll
            for (int nt = 0; nt < 2; ++nt) {
                h8 bv_ = *(const h8*)(&vT[w][nt * 16 + cl][g * 8]);
                ov[nt] = __builtin_amdgcn_mfma_f32_16x16x32_f16(ap, bv_, ov[nt], 0, 0, 0);
            }
            // O_h -> tmpu with the deferred 1/sum folded in, then incr. proj
#pragma unroll
            for (int r = 0; r < 4; ++r)
                tmpu[wave][g * 4 + r][cl] = pack2(ov[0][r] * invr[r], ov[1][r] * invr[r]);
            h8 am = *(const h8*)(&tmpu[wave][cl][g * 4]);
            const _Float16* pp_h = projp + (long)h * 12 * 64 * 8;
#pragma unroll
            for (int nt = 0; nt < 12; ++nt) {
                h8 bp = *(const h8*)(pp_h + ((nt * 64 + lane) << 3));
                pacc[nt] = __builtin_amdgcn_mfma_f32_16x16x32_f16(am, bp, pacc[nt], 0, 0, 0);
            }
        }
        // loop: next alpha drains vmcnt (stage h+1) before touching wbuf
    }

    // ================= Final store: out = pacc + proj_b =================
#pragma unroll
    for (int r = 0; r < 4; ++r) {
        long grow = (long)(w0 + w) * 64 + S_of(mh * 16 + g * 4 + r);
        float* po_ = out + grow * 192 + cl;
#pragma unroll
        for (int nt = 0; nt < 12; ++nt)
            po_[nt * 16] = pacc[nt][r] + proj_b[nt * 16 + cl];
    }
}

extern "C" void kernel_launch(void* const* d_in, const int* in_sizes, int n_in,
                              void* d_out, int out_size, void* d_ws, size_t ws_size,
                              hipStream_t stream) {
    const float* x = (const float*)d_in[0];
    const float* qkv_w = (const float*)d_in[1];
    const float* qkv_b = (const float*)d_in[2];
    const float* proj_w = (const float*)d_in[3];
    const float* proj_b = (const float*)d_in[4];
    const float* logit_scale = (const float*)d_in[5];
    const float* rel_bias_table = (const float*)d_in[6];
    const int* rel_pos_index = (const int*)d_in[7];
    float* out = (float*)d_out;

    const int B = in_sizes[0] / (64 * 192);   // number of windows (8192)

    _Float16* qkvp = (_Float16*)d_ws;                 // 13824*8 f16
    _Float16* projp = qkvp + 6 * 6 * 6 * 64 * 8;      // 4608*8 f16
    float* b2t = (float*)(projp + 6 * 12 * 64 * 8);   // 6*32*32 f32
    float* sl2t = b2t + 6 * 32 * 32;                  // 6 f32

    pack_kernel<<<96, 256, 0, stream>>>(qkv_w, proj_w, rel_bias_table, rel_pos_index,
                                        logit_scale, qkvp, projp, b2t, sl2t);
    cwa_kernel<<<B / 2, 256, 0, stream>>>(x, qkvp, projp, b2t, sl2t, qkv_b, proj_b,
                                          out);
}

// Round 11
// 218.184 us; speedup vs baseline: 1.4328x; 1.0030x over previous
//
#include <hip/hip_runtime.h>

typedef _Float16 h8 __attribute__((ext_vector_type(8)));
typedef _Float16 h2 __attribute__((ext_vector_type(2)));
typedef float f4 __attribute__((ext_vector_type(4)));

#define NHEADS 6
#define LOGMAX 4.6051701859880914f   // ln(100)
#define LOG2E  1.4426950408889634f

// kept position j (0..31) -> row index in window (0..63); kept iff (r+c) even
__device__ __forceinline__ int S_of(int j) { return ((j >> 2) << 3) + ((j & 3) << 1) + ((j >> 2) & 1); }
// complement (masked) position
__device__ __forceinline__ int SC_of(int j) { return ((j >> 2) << 3) + ((j & 3) << 1) + (1 - ((j >> 2) & 1)); }

// 16-lane (DPP row) reductions on the VALU pipe.
template <int CTRL>
__device__ __forceinline__ float dpp_mov(float x) {
    return __builtin_bit_cast(float,
        __builtin_amdgcn_update_dpp(0, __builtin_bit_cast(int, x), CTRL, 0xF, 0xF, true));
}
__device__ __forceinline__ float rowsum16(float x) {
    x += dpp_mov<0x121>(x);   // row_ror:1
    x += dpp_mov<0x122>(x);   // row_ror:2
    x += dpp_mov<0x124>(x);   // row_ror:4
    x += dpp_mov<0x128>(x);   // row_ror:8
    return x;
}
__device__ __forceinline__ unsigned pack2(float a, float b) {
    h2 v; v[0] = (_Float16)a; v[1] = (_Float16)b;
    return __builtin_bit_cast(unsigned, v);
}
// single-instruction transcendentals (avoid libm div/sqrt expansions)
__device__ __forceinline__ float fast_exp2(float x) {
    float r; asm("v_exp_f32 %0, %1" : "=v"(r) : "v"(x)); return r;
}
__device__ __forceinline__ float fast_rcp(float x) {
    float r; asm("v_rcp_f32 %0, %1" : "=v"(r) : "v"(x)); return r;
}
__device__ __forceinline__ float fast_rsq(float x) {
    float r; asm("v_rsq_f32 %0, %1" : "=v"(r) : "v"(x)); return r;
}

// ---------------------------------------------------------------------------
// Pack kernel (unchanged from round 10).
// qkvp: [h][nt 0..5][ks 0..5][lane][8]
// projp: [ksblk=h][nt 0..11][lane][8], k-dim pair-interleaved per head block
// b2t:  [h][32][32] = (bias - scale_h - 1) * LOG2E   (constant-shift softmax)
// sl2t: [h] = scale_h * LOG2E
// ---------------------------------------------------------------------------
__global__ void pack_kernel(const float* __restrict__ qkv_w,
                            const float* __restrict__ proj_w,
                            const float* __restrict__ rel_bias_table,
                            const int* __restrict__ rel_pos_index,
                            const float* __restrict__ logit_scale,
                            _Float16* __restrict__ qkvp,
                            _Float16* __restrict__ projp,
                            float* __restrict__ b2t,
                            float* __restrict__ sl2t) {
    int tid = blockIdx.x * 256 + threadIdx.x;
    const int NQ = 6 * 6 * 6 * 64;        // 13824
    const int NP = 6 * 12 * 64;           // 4608
    if (tid < NQ) {
        int l = tid & 63;
        int rest = tid >> 6;
        int ks = rest % 6;
        int nt = (rest / 6) % 6;
        int h = rest / 36;
        int o = (nt >> 1) * 192 + h * 32 + (nt & 1) * 16 + (l & 15);
        int k0 = ks * 32 + (l >> 4) * 8;
        const float* src = qkv_w + o * 192 + k0;
        _Float16* dst = qkvp + tid * 8;
#pragma unroll
        for (int j = 0; j < 8; ++j) dst[j] = (_Float16)src[j];
    } else if (tid < NQ + NP) {
        int t = tid - NQ;
        int l = t & 63;
        int rest = t >> 6;         // 0..71
        int nt = rest % 12;
        int h = rest / 12;         // k-block (head)
        int o = nt * 16 + (l & 15);
        const float* srcrow = proj_w + o * 192 + h * 32;
        _Float16* dst = projp + t * 8;
        int p0 = (l >> 4) * 8;
#pragma unroll
        for (int j = 0; j < 8; ++j) {
            int p = p0 + j;
            dst[j] = (_Float16)srcrow[(p >> 1) + ((p & 1) << 4)];
        }
    } else if (tid < NQ + NP + 6 * 32 * 32) {
        int t = tid - (NQ + NP);
        int h = t >> 10;
        int jr = (t >> 5) & 31;
        int ic = t & 31;
        int rp = rel_pos_index[S_of(jr) * 64 + S_of(ic)];
        float scale = __expf(fminf(logit_scale[h], LOGMAX));
        b2t[t] = (rel_bias_table[rp * NHEADS + h] - scale - 1.0f) * LOG2E;
        if (jr == 0 && ic == 0) sl2t[h] = scale * LOG2E;
    }
}

// ---------------------------------------------------------------------------
// Main fused kernel: 256 thr = 4 waves = FOUR windows; wave = whole window
// (M=32: xf[2][6]). Round-10 arithmetic showed the LDS pipe (~90 µs) is
// co-dominant with HBM: phase-A's 36 B-frag ds_reads were duplicated by the
// 2 waves sharing a window. M=32 reuses each B-frag for 2 m-tiles (LDS reads
// per window halved), makes kn/vT/tmpu WAVE-PRIVATE (gamma barrier gone:
// 2 barriers/head, wbuf only), and amortizes the wbuf DMA over 4 windows.
// pacc[2][12]+xf[2][6] ~ 220 regs -> waves_per_eu(2,2) hard-pins the 256-reg
// tier (allocator choosing smaller tiers caused the r2/r9 spill disasters).
// LDS 67584 B -> 2 blocks/CU = 8 waves, matching the reg tier exactly.
// ---------------------------------------------------------------------------
__global__ __launch_bounds__(256) __attribute__((amdgpu_waves_per_eu(2, 2)))
void cwa_kernel(
    const float* __restrict__ x,
    const _Float16* __restrict__ qkvp,
    const _Float16* __restrict__ projp,
    const float* __restrict__ b2t,
    const float* __restrict__ sl2t,
    const float* __restrict__ qkv_b,
    const float* __restrict__ proj_b,
    float* __restrict__ out) {
    __shared__ __align__(16) _Float16 wbuf[6 * 6 * 64 * 8];   // 36864 B head tile
    __shared__ __align__(16) unsigned knu[4][32][20];         // 10240 B (wave-priv)
    __shared__ __align__(16) _Float16 vT[4][32][40];          // 10240 B (wave-priv)
    __shared__ __align__(16) unsigned tmpu[4][32][20];        // 10240 B (q/p/O)
    // total 67584 B -> 2 blocks/CU

    const int tid = threadIdx.x;
    const int lane = tid & 63;
    const int wave = tid >> 6;
    const int cl = lane & 15;
    const int g = lane >> 4;
    const long w0 = (long)blockIdx.x * 4;
    const long win = w0 + wave;     // this wave's window

    // ---- async-stage head h's weight tile: 9 chunks of 1 KB per wave ----
    auto stage = [&](int h) {
        const _Float16* srcb = qkvp + (long)h * (6 * 6 * 64 * 8) + (wave * 9) * 512 + lane * 8;
        _Float16* dstb = &wbuf[(wave * 9) * 512];
#pragma unroll
        for (int c = 0; c < 9; ++c)
            __builtin_amdgcn_global_load_lds(
                (const __attribute__((address_space(1))) unsigned*)(srcb + c * 512),
                (__attribute__((address_space(3))) unsigned*)(dstb + c * 512),
                16, 0, 0);
    };

    stage(0);   // DMA flies under the prologue below

    // ---- masked rows: output = proj_b (4 windows x 32 rows x 48 f4) ----
#pragma unroll
    for (int it = 0; it < 24; ++it) {
        int e = tid + it * 256;            // 0..6143
        int wl = e / 1536;
        int rem = e - wl * 1536;
        int row = rem / 48, c4 = rem - row * 48;
        *(f4*)(out + ((w0 + wl) * 64 + SC_of(row)) * 192 + c4 * 4) =
            *(const f4*)(proj_b + c4 * 4);
    }

    // ---- this wave's 32 kept x-rows -> A-fragment registers (2 m-tiles) ----
    h8 xf[2][6];
#pragma unroll
    for (int mt = 0; mt < 2; ++mt) {
        long xbase = (win * 64 + S_of(mt * 16 + cl)) * 192;
#pragma unroll
        for (int ks = 0; ks < 6; ++ks) {
            f4 u0 = *(const f4*)(x + xbase + ks * 32 + g * 8);
            f4 u1 = *(const f4*)(x + xbase + ks * 32 + g * 8 + 4);
            h8 hv;
            hv[0] = (_Float16)u0[0]; hv[1] = (_Float16)u0[1];
            hv[2] = (_Float16)u0[2]; hv[3] = (_Float16)u0[3];
            hv[4] = (_Float16)u1[0]; hv[5] = (_Float16)u1[1];
            hv[6] = (_Float16)u1[2]; hv[7] = (_Float16)u1[3];
            xf[mt][ks] = hv;
        }
    }

    f4 pacc[2][12];
#pragma unroll
    for (int mt = 0; mt < 2; ++mt)
#pragma unroll
        for (int nt = 0; nt < 12; ++nt) pacc[mt][nt] = 0.0f;

#pragma unroll 1
    for (int h = 0; h < NHEADS; ++h) {
        // ---- barrier alpha: everyone's stage DMA for head h has landed ----
        asm volatile("s_waitcnt vmcnt(0)" ::: "memory");
        __builtin_amdgcn_s_barrier();

        // ============ Phase A: qkv GEMM from wbuf, M=32 (72 MFMA) ===========
        f4 acc[2][6];
#pragma unroll
        for (int mt = 0; mt < 2; ++mt)
#pragma unroll
            for (int nt = 0; nt < 6; ++nt) acc[mt][nt] = 0.0f;
#pragma unroll
        for (int ks = 0; ks < 6; ++ks) {
#pragma unroll
            for (int nt = 0; nt < 6; ++nt) {
                h8 b = *(const h8*)(&wbuf[((nt * 6 + ks) * 64 + lane) * 8]);
                acc[0][nt] = __builtin_amdgcn_mfma_f32_16x16x32_f16(xf[0][ks], b, acc[0][nt], 0, 0, 0);
                acc[1][nt] = __builtin_amdgcn_mfma_f32_16x16x32_f16(xf[1][ks], b, acc[1][nt], 0, 0, 0);
            }
        }
        // ---- barrier beta: all waves done reading wbuf -> safe to overwrite
        asm volatile("s_waitcnt lgkmcnt(0)" ::: "memory");
        __builtin_amdgcn_s_barrier();
        if (h + 1 < NHEADS) stage(h + 1);   // DMA overlaps epilogue + attention

        // ---- epilogue (wave-private; rsq, DPP sums) ----
        float bq0 = qkv_b[h * 32 + cl], bq1 = qkv_b[h * 32 + 16 + cl];
        float bk0 = qkv_b[192 + h * 32 + cl], bk1 = qkv_b[192 + h * 32 + 16 + cl];
        float bv0 = qkv_b[384 + h * 32 + cl], bv1 = qkv_b[384 + h * 32 + 16 + cl];
#pragma unroll
        for (int mt = 0; mt < 2; ++mt)
#pragma unroll
            for (int r = 0; r < 4; ++r) {
                int row = mt * 16 + g * 4 + r;
                float t0 = acc[mt][0][r] + bq0, t1 = acc[mt][1][r] + bq1;
                float ss = rowsum16(fmaf(t0, t0, t1 * t1));
                float rs = fast_rsq(fmaxf(ss, 1e-24f));
                tmpu[wave][row][cl] = pack2(t0 * rs, t1 * rs);
                t0 = acc[mt][2][r] + bk0; t1 = acc[mt][3][r] + bk1;
                ss = rowsum16(fmaf(t0, t0, t1 * t1));
                rs = fast_rsq(fmaxf(ss, 1e-24f));
                knu[wave][row][cl] = pack2(t0 * rs, t1 * rs);
                int pos = 2 * (g * 4 + r) + mt;   // kv pair-interleave
                vT[wave][cl][pos] = (_Float16)(acc[mt][4][r] + bv0);
                vT[wave][16 + cl][pos] = (_Float16)(acc[mt][5][r] + bv1);
            }
        // NO barrier: kn/vT/tmpu are wave-private; per-wave LDS order suffices

        // ============ Attention (whole window, wave-private) ================
        {
            h8 aq0 = *(const h8*)(&tmpu[wave][cl][g * 4]);
            h8 aq1 = *(const h8*)(&tmpu[wave][16 + cl][g * 4]);
            h8 bk0_ = *(const h8*)(&knu[wave][cl][g * 4]);
            h8 bk1_ = *(const h8*)(&knu[wave][16 + cl][g * 4]);
            f4 s[2][2];
            s[0][0] = 0.0f; s[0][1] = 0.0f; s[1][0] = 0.0f; s[1][1] = 0.0f;
            s[0][0] = __builtin_amdgcn_mfma_f32_16x16x32_f16(aq0, bk0_, s[0][0], 0, 0, 0);
            s[0][1] = __builtin_amdgcn_mfma_f32_16x16x32_f16(aq0, bk1_, s[0][1], 0, 0, 0);
            s[1][0] = __builtin_amdgcn_mfma_f32_16x16x32_f16(aq1, bk0_, s[1][0], 0, 0, 0);
            s[1][1] = __builtin_amdgcn_mfma_f32_16x16x32_f16(aq1, bk1_, s[1][1], 0, 0, 0);

            float sl2 = sl2t[h];
            float invr[2][4];
#pragma unroll
            for (int mt = 0; mt < 2; ++mt)
#pragma unroll
                for (int r = 0; r < 4; ++r) {
                    int row = mt * 16 + g * 4 + r;
                    float e0 = fast_exp2(fmaf(s[mt][0][r], sl2, b2t[h * 1024 + row * 32 + cl]));
                    float e1 = fast_exp2(fmaf(s[mt][1][r], sl2, b2t[h * 1024 + row * 32 + 16 + cl]));
                    invr[mt][r] = rowsum16(e0 + e1);
                    tmpu[wave][row][cl] = pack2(e0, e1);   // unnormalized P
                }
#pragma unroll
            for (int mt = 0; mt < 2; ++mt)
#pragma unroll
                for (int r = 0; r < 4; ++r) invr[mt][r] = fast_rcp(invr[mt][r]);

            h8 ap0 = *(const h8*)(&tmpu[wave][cl][g * 4]);
            h8 ap1 = *(const h8*)(&tmpu[wave][16 + cl][g * 4]);
            h8 bv0_ = *(const h8*)(&vT[wave][cl][g * 8]);
            h8 bv1_ = *(const h8*)(&vT[wave][16 + cl][g * 8]);
            f4 ov[2][2];
            ov[0][0] = 0.0f; ov[0][1] = 0.0f; ov[1][0] = 0.0f; ov[1][1] = 0.0f;
            ov[0][0] = __builtin_amdgcn_mfma_f32_16x16x32_f16(ap0, bv0_, ov[0][0], 0, 0, 0);
            ov[0][1] = __builtin_amdgcn_mfma_f32_16x16x32_f16(ap0, bv1_, ov[0][1], 0, 0, 0);
            ov[1][0] = __builtin_amdgcn_mfma_f32_16x16x32_f16(ap1, bv0_, ov[1][0], 0, 0, 0);
            ov[1][1] = __builtin_amdgcn_mfma_f32_16x16x32_f16(ap1, bv1_, ov[1][1], 0, 0, 0);

            // O_h (1/sum folded) -> tmpu, then incremental proj from L2 frags
#pragma unroll
            for (int mt = 0; mt < 2; ++mt)
#pragma unroll
                for (int r = 0; r < 4; ++r)
                    tmpu[wave][mt * 16 + g * 4 + r][cl] =
                        pack2(ov[mt][0][r] * invr[mt][r], ov[mt][1][r] * invr[mt][r]);
            h8 am0 = *(const h8*)(&tmpu[wave][cl][g * 4]);
            h8 am1 = *(const h8*)(&tmpu[wave][16 + cl][g * 4]);
            const _Float16* pp_h = projp + (long)h * 12 * 64 * 8;
#pragma unroll
            for (int nt = 0; nt < 12; ++nt) {
                h8 bp = *(const h8*)(pp_h + ((nt * 64 + lane) << 3));
                pacc[0][nt] = __builtin_amdgcn_mfma_f32_16x16x32_f16(am0, bp, pacc[0][nt], 0, 0, 0);
                pacc[1][nt] = __builtin_amdgcn_mfma_f32_16x16x32_f16(am1, bp, pacc[1][nt], 0, 0, 0);
            }
        }
        // loop: next alpha drains vmcnt (stage h+1) before touching wbuf
    }

    // ================= Final store: out = pacc + proj_b =================
#pragma unroll
    for (int mt = 0; mt < 2; ++mt)
#pragma unroll
        for (int r = 0; r < 4; ++r) {
            long grow = win * 64 + S_of(mt * 16 + g * 4 + r);
            float* po_ = out + grow * 192 + cl;
#pragma unroll
            for (int nt = 0; nt < 12; ++nt)
                po_[nt * 16] = pacc[mt][nt][r] + proj_b[nt * 16 + cl];
        }
}

extern "C" void kernel_launch(void* const* d_in, const int* in_sizes, int n_in,
                              void* d_out, int out_size, void* d_ws, size_t ws_size,
                              hipStream_t stream) {
    const float* x = (const float*)d_in[0];
    const float* qkv_w = (const float*)d_in[1];
    const float* qkv_b = (const float*)d_in[2];
    const float* proj_w = (const float*)d_in[3];
    const float* proj_b = (const float*)d_in[4];
    const float* logit_scale = (const float*)d_in[5];
    const float* rel_bias_table = (const float*)d_in[6];
    const int* rel_pos_index = (const int*)d_in[7];
    float* out = (float*)d_out;

    const int B = in_sizes[0] / (64 * 192);   // number of windows (8192)

    _Float16* qkvp = (_Float16*)d_ws;                 // 13824*8 f16
    _Float16* projp = qkvp + 6 * 6 * 6 * 64 * 8;      // 4608*8 f16
    float* b2t = (float*)(projp + 6 * 12 * 64 * 8);   // 6*32*32 f32
    float* sl2t = b2t + 6 * 32 * 32;                  // 6 f32

    pack_kernel<<<96, 256, 0, stream>>>(qkv_w, proj_w, rel_bias_table, rel_pos_index,
                                        logit_scale, qkvp, projp, b2t, sl2t);
    cwa_kernel<<<B / 4, 256, 0, stream>>>(x, qkvp, projp, b2t, sl2t, qkv_b, proj_b,
                                          out);
}